// Round 2
// baseline (289.989 us; speedup 1.0000x reference)
//
#include <hip/hip_runtime.h>
#include <hip/hip_bf16.h>

// LSTM cell, B=4096, IN=1024, H=1024, K = IN+H = 2048. All I/O float32.
// gates = X @ W^T (+b), X=[B,2048] concat(input,hx), W=[4H,2048].
// Block computes 128 batch rows x (32 hidden cols x 4 gates) = 128x128 gate
// tile via bf16 MFMA (inputs converted fp32->bf16 in registers at staging),
// then applies the LSTM gating fused in-register. fp32 accumulate/output.

typedef __attribute__((ext_vector_type(8))) __bf16 bf16x8;
typedef __attribute__((ext_vector_type(4))) float f32x4;

__device__ __forceinline__ unsigned short f2bf(float f) {
  union { float f; unsigned int u; } v; v.f = f;
  unsigned int u = v.u + 0x7FFF + ((v.u >> 16) & 1);  // round-to-nearest-even
  return (unsigned short)(u >> 16);
}
__device__ __forceinline__ unsigned int pack2(float a, float b) {
  return (unsigned int)f2bf(a) | ((unsigned int)f2bf(b) << 16);
}

__device__ __forceinline__ float sigmoidf_fast(float x) {
  return 1.0f / (1.0f + __expf(-x));
}
__device__ __forceinline__ float tanhf_fast(float x) {
  return 1.0f - 2.0f / (__expf(2.0f * x) + 1.0f);
}

__global__ __launch_bounds__(256) void lstm_fused(
    const float* __restrict__ xin, const float* __restrict__ hx,
    const float* __restrict__ cx,
    const float* __restrict__ Wi, const float* __restrict__ bi,
    const float* __restrict__ Wf, const float* __restrict__ bfv,
    const float* __restrict__ Wg, const float* __restrict__ bg,
    const float* __restrict__ Wo, const float* __restrict__ bo,
    float* __restrict__ out) {
  __shared__ unsigned short As[128 * 32];  // X tile (bf16): [row 0..128)[k 0..32)
  __shared__ unsigned short Bs[128 * 32];  // W tile (bf16): row rb -> (gate,hn) permuted

  const int tid = threadIdx.x;
  const int lane = tid & 63;
  const int wid = tid >> 6;
  const int wr = wid >> 1, wc = wid & 1;
  const int lane15 = lane & 15, quad = lane >> 4;

  const int mbase = blockIdx.x * 128;  // batch tile
  const int nbase = blockIdx.y * 32;   // hidden-col tile

  // ---- staging: thread handles chunks c=tid and c=tid+256; chunk c = 8 elems
  // at LDS shorts [c*8, c*8+8). row = c>>2, kofs = (c&3)*8.
  const int kofs = (tid & 3) * 8;
  const size_t a_off0 = (size_t)(mbase + (tid >> 2)) * 1024 + kofs;
  const size_t a_off1 = a_off0 + (size_t)64 * 1024;

  auto wsel = [&](int g) {
    return g == 0 ? Wi : (g == 1 ? Wf : (g == 2 ? Wg : Wo));
  };
  const int rb0 = tid >> 2;
  const int rb1 = rb0 + 64;
  // fragment mapping: col_local -> gate=(col>>4)&3, hn=(col>>6)*16+(col&15)
  const float* bsrc0 =
      wsel((rb0 >> 4) & 3) + (size_t)(nbase + (rb0 >> 6) * 16 + (rb0 & 15)) * 2048 + kofs;
  const float* bsrc1 =
      wsel((rb1 >> 4) & 3) + (size_t)(nbase + (rb1 >> 6) * 16 + (rb1 & 15)) * 2048 + kofs;

  uint4* lA0 = (uint4*)(As + (size_t)tid * 8);
  uint4* lA1 = (uint4*)(As + (size_t)(tid + 256) * 8);
  uint4* lB0 = (uint4*)(Bs + (size_t)tid * 8);
  uint4* lB1 = (uint4*)(Bs + (size_t)(tid + 256) * 8);

  f32x4 acc[4][4] = {};

  for (int kt = 0; kt < 64; ++kt) {
    const int kc = kt * 32;
    const float* abase = (kc < 1024 ? xin : hx) + (kc & 1023);

    // global loads (fp32) -> registers
    const float4 a0lo = *(const float4*)(abase + a_off0);
    const float4 a0hi = *(const float4*)(abase + a_off0 + 4);
    const float4 a1lo = *(const float4*)(abase + a_off1);
    const float4 a1hi = *(const float4*)(abase + a_off1 + 4);
    const float4 b0lo = *(const float4*)(bsrc0 + kc);
    const float4 b0hi = *(const float4*)(bsrc0 + kc + 4);
    const float4 b1lo = *(const float4*)(bsrc1 + kc);
    const float4 b1hi = *(const float4*)(bsrc1 + kc + 4);

    uint4 pa0, pa1, pb0, pb1;
    pa0.x = pack2(a0lo.x, a0lo.y); pa0.y = pack2(a0lo.z, a0lo.w);
    pa0.z = pack2(a0hi.x, a0hi.y); pa0.w = pack2(a0hi.z, a0hi.w);
    pa1.x = pack2(a1lo.x, a1lo.y); pa1.y = pack2(a1lo.z, a1lo.w);
    pa1.z = pack2(a1hi.x, a1hi.y); pa1.w = pack2(a1hi.z, a1hi.w);
    pb0.x = pack2(b0lo.x, b0lo.y); pb0.y = pack2(b0lo.z, b0lo.w);
    pb0.z = pack2(b0hi.x, b0hi.y); pb0.w = pack2(b0hi.z, b0hi.w);
    pb1.x = pack2(b1lo.x, b1lo.y); pb1.y = pack2(b1lo.z, b1lo.w);
    pb1.z = pack2(b1hi.x, b1hi.y); pb1.w = pack2(b1hi.z, b1hi.w);

    __syncthreads();  // previous iteration's fragment reads complete
    *lA0 = pa0;
    *lA1 = pa1;
    *lB0 = pb0;
    *lB1 = pb1;
    __syncthreads();  // staging visible

    bf16x8 a[4], b[4];
#pragma unroll
    for (int i = 0; i < 4; ++i)
      a[i] = *reinterpret_cast<const bf16x8*>(&As[(wr * 64 + i * 16 + lane15) * 32 + quad * 8]);
#pragma unroll
    for (int j = 0; j < 4; ++j)
      b[j] = *reinterpret_cast<const bf16x8*>(&Bs[(wc * 64 + j * 16 + lane15) * 32 + quad * 8]);
#pragma unroll
    for (int i = 0; i < 4; ++i)
#pragma unroll
      for (int j = 0; j < 4; ++j)
        acc[i][j] = __builtin_amdgcn_mfma_f32_16x16x32_bf16(a[i], b[j], acc[i][j], 0, 0, 0);
  }

  // ---- fused LSTM epilogue ----
  // acc[i][j]: j is the gate (0:i 1:f 2:g 3:o); C layout: col=lane&15, row=quad*4+reg
  const int n = nbase + wc * 16 + lane15;
  const float bias_i = bi[n];
  const float bias_f = bfv[n];
  const float bias_g = bg[n];
  const float bias_o = bo[n];

  float* outh = out;
  float* outc = out + (size_t)4096 * 1024;

#pragma unroll
  for (int i = 0; i < 4; ++i) {
#pragma unroll
    for (int r = 0; r < 4; ++r) {
      const int mb = mbase + wr * 64 + i * 16 + quad * 4 + r;
      const size_t idx = (size_t)mb * 1024 + n;
      const float it = sigmoidf_fast(acc[i][0][r] + bias_i);
      const float ft = sigmoidf_fast(acc[i][1][r] + bias_f);
      const float gt = tanhf_fast(acc[i][2][r] + bias_g);
      const float ot = sigmoidf_fast(acc[i][3][r] + bias_o);
      const float cv = ft * cx[idx] + it * gt;
      const float hv = ot * tanhf_fast(cv);
      outh[idx] = hv;
      outc[idx] = cv;
    }
  }
}

extern "C" void kernel_launch(void* const* d_in, const int* in_sizes, int n_in,
                              void* d_out, int out_size, void* d_ws, size_t ws_size,
                              hipStream_t stream) {
  const float* xin = (const float*)d_in[0];
  const float* hx  = (const float*)d_in[1];
  const float* cx  = (const float*)d_in[2];
  const float* Wi  = (const float*)d_in[3];
  const float* bi  = (const float*)d_in[4];
  const float* Wf  = (const float*)d_in[5];
  const float* bf  = (const float*)d_in[6];
  const float* Wg  = (const float*)d_in[7];
  const float* bg  = (const float*)d_in[8];
  const float* Wo  = (const float*)d_in[9];
  const float* bo  = (const float*)d_in[10];
  float* out = (float*)d_out;

  dim3 grid(4096 / 128, 1024 / 32);  // 32 x 32 = 1024 blocks
  lstm_fused<<<grid, 256, 0, stream>>>(xin, hx, cx, Wi, bi, Wf, bf, Wg, bg, Wo, bo, out);
}

// Round 3
// 229.968 us; speedup vs baseline: 1.2610x; 1.2610x over previous
//
#include <hip/hip_runtime.h>
#include <hip/hip_bf16.h>

// LSTM cell, B=4096, IN=1024, H=1024, K = IN+H = 2048. All I/O float32.
// Two passes:
//  1) convert_pack: X=concat(input,hx) -> bf16 Xb[4096][2048]; W -> bf16
//     Wp[4096][2048] permuted so GEMM B-tiles are contiguous rows.
//  2) lstm_gemm: m97-style 128x128 MFMA GEMM (global_load_lds staging) with
//     fused LSTM gating epilogue. fp32 accumulate/output.

typedef __attribute__((ext_vector_type(8))) __bf16 bf16x8;
typedef __attribute__((ext_vector_type(4))) float f32x4;

__device__ __forceinline__ unsigned short f2bf(float f) {
  union { float f; unsigned int u; } v; v.f = f;
  unsigned int u = v.u + 0x7FFF + ((v.u >> 16) & 1);  // round-to-nearest-even
  return (unsigned short)(u >> 16);
}
__device__ __forceinline__ unsigned int pack2(float a, float b) {
  return (unsigned int)f2bf(a) | ((unsigned int)f2bf(b) << 16);
}

__device__ __forceinline__ void gld_lds16(const void* g, void* l) {
  __builtin_amdgcn_global_load_lds(
      (const __attribute__((address_space(1))) unsigned int*)g,
      (__attribute__((address_space(3))) unsigned int*)l, 16, 0, 0);
}

__device__ __forceinline__ float sigmoidf_fast(float x) {
  return 1.0f / (1.0f + __expf(-x));
}
__device__ __forceinline__ float tanhf_fast(float x) {
  return 1.0f - 2.0f / (__expf(2.0f * x) + 1.0f);
}

// ---------------- Pass 1: fp32 -> bf16 conversion + W permutation ----------
// 2^21 threads, each converts 8 elements (16B out).
__global__ __launch_bounds__(256) void convert_pack(
    const float* __restrict__ xin, const float* __restrict__ hx,
    const float* __restrict__ Wi, const float* __restrict__ Wf,
    const float* __restrict__ Wg, const float* __restrict__ Wo,
    unsigned short* __restrict__ Xb, unsigned short* __restrict__ Wp) {
  const int t = blockIdx.x * 256 + threadIdx.x;
  const float* src;
  unsigned short* dst;
  if (t < (1 << 20)) {
    const int e = t * 8;
    const int row = e >> 11, k = e & 2047;
    src = (k < 1024) ? (xin + (size_t)row * 1024 + k)
                     : (hx + (size_t)row * 1024 + (k - 1024));
    dst = Xb + e;
  } else {
    const int e = (t - (1 << 20)) * 8;
    const int g_rb = e >> 11, k = e & 2047;
    const int nb = g_rb >> 7, rb = g_rb & 127;
    const int gate = (rb >> 4) & 3;
    const int hn = (rb >> 6) * 16 + (rb & 15);
    const float* W = gate == 0 ? Wi : (gate == 1 ? Wf : (gate == 2 ? Wg : Wo));
    src = W + (size_t)(nb * 32 + hn) * 2048 + k;
    dst = Wp + e;
  }
  const float4 lo = *(const float4*)src;
  const float4 hi = *(const float4*)(src + 4);
  uint4 p;
  p.x = pack2(lo.x, lo.y);
  p.y = pack2(lo.z, lo.w);
  p.z = pack2(hi.x, hi.y);
  p.w = pack2(hi.z, hi.w);
  *(uint4*)dst = p;
}

// ---------------- Pass 2: MFMA GEMM + fused LSTM gating --------------------
__global__ __launch_bounds__(256) void lstm_gemm(
    const unsigned short* __restrict__ Xb, const unsigned short* __restrict__ Wp,
    const float* __restrict__ cx,
    const float* __restrict__ bi, const float* __restrict__ bfv,
    const float* __restrict__ bg, const float* __restrict__ bo,
    float* __restrict__ out) {
  __shared__ unsigned short As[128 * 32];  // X tile: [row][k]
  __shared__ unsigned short Bs[128 * 32];  // W tile: permuted rows

  const int tid = threadIdx.x;
  const int lane = tid & 63;
  const int wid = tid >> 6;
  const int wr = wid >> 1, wc = wid & 1;
  const int lane15 = lane & 15, quad = lane >> 4;

  const int mbase = blockIdx.x * 128;  // batch tile
  const int nb = blockIdx.y;           // hidden-col tile (32 cols)
  const int nbase = nb * 32;

  // chunk c = 16B: row = c>>2, kofs = (c&3)*8; thread handles c=tid, c=tid+256
  const int kofs = (tid & 3) * 8;
  const unsigned short* asrc0 = Xb + (size_t)(mbase + (tid >> 2)) * 2048 + kofs;
  const unsigned short* asrc1 = asrc0 + (size_t)64 * 2048;
  const unsigned short* bsrc0 = Wp + (size_t)(nb * 128 + (tid >> 2)) * 2048 + kofs;
  const unsigned short* bsrc1 = bsrc0 + (size_t)64 * 2048;

  unsigned short* lA0 = As + tid * 8;
  unsigned short* lA1 = As + (tid + 256) * 8;
  unsigned short* lB0 = Bs + tid * 8;
  unsigned short* lB1 = Bs + (tid + 256) * 8;

  f32x4 acc[4][4] = {};

  for (int kt = 0; kt < 64; ++kt) {
    const int kc = kt * 32;
    gld_lds16(asrc0 + kc, lA0);
    gld_lds16(asrc1 + kc, lA1);
    gld_lds16(bsrc0 + kc, lB0);
    gld_lds16(bsrc1 + kc, lB1);
    __syncthreads();  // DMA landed (vmcnt drain) + all waves staged

    bf16x8 a[4], b[4];
#pragma unroll
    for (int i = 0; i < 4; ++i)
      a[i] = *reinterpret_cast<const bf16x8*>(&As[(wr * 64 + i * 16 + lane15) * 32 + quad * 8]);
#pragma unroll
    for (int j = 0; j < 4; ++j)
      b[j] = *reinterpret_cast<const bf16x8*>(&Bs[(wc * 64 + j * 16 + lane15) * 32 + quad * 8]);
#pragma unroll
    for (int i = 0; i < 4; ++i)
#pragma unroll
      for (int j = 0; j < 4; ++j)
        acc[i][j] = __builtin_amdgcn_mfma_f32_16x16x32_bf16(a[i], b[j], acc[i][j], 0, 0, 0);
    __syncthreads();  // all reads done before next iteration's DMA overwrites
  }

  // fused LSTM epilogue: acc[i][j], j = gate (0:i 1:f 2:g 3:o);
  // C layout: col=lane&15, row=quad*4+reg
  const int n = nbase + wc * 16 + lane15;
  const float bias_i = bi[n];
  const float bias_f = bfv[n];
  const float bias_g = bg[n];
  const float bias_o = bo[n];

  float* outh = out;
  float* outc = out + (size_t)4096 * 1024;

#pragma unroll
  for (int i = 0; i < 4; ++i) {
#pragma unroll
    for (int r = 0; r < 4; ++r) {
      const int mb = mbase + wr * 64 + i * 16 + quad * 4 + r;
      const size_t idx = (size_t)mb * 1024 + n;
      const float it = sigmoidf_fast(acc[i][0][r] + bias_i);
      const float ft = sigmoidf_fast(acc[i][1][r] + bias_f);
      const float gt = tanhf_fast(acc[i][2][r] + bias_g);
      const float ot = sigmoidf_fast(acc[i][3][r] + bias_o);
      const float cv = ft * cx[idx] + it * gt;
      const float hv = ot * tanhf_fast(cv);
      outh[idx] = hv;
      outc[idx] = cv;
    }
  }
}

// ---------------- Fallback (R2): single fused kernel, no workspace ----------
__global__ __launch_bounds__(256) void lstm_fused_fb(
    const float* __restrict__ xin, const float* __restrict__ hx,
    const float* __restrict__ cx,
    const float* __restrict__ Wi, const float* __restrict__ bi,
    const float* __restrict__ Wf, const float* __restrict__ bfv,
    const float* __restrict__ Wg, const float* __restrict__ bg,
    const float* __restrict__ Wo, const float* __restrict__ bo,
    float* __restrict__ out) {
  __shared__ unsigned short As[128 * 32];
  __shared__ unsigned short Bs[128 * 32];

  const int tid = threadIdx.x;
  const int lane = tid & 63;
  const int wid = tid >> 6;
  const int wr = wid >> 1, wc = wid & 1;
  const int lane15 = lane & 15, quad = lane >> 4;
  const int mbase = blockIdx.x * 128;
  const int nbase = blockIdx.y * 32;

  const int kofs = (tid & 3) * 8;
  const size_t a_off0 = (size_t)(mbase + (tid >> 2)) * 1024 + kofs;
  const size_t a_off1 = a_off0 + (size_t)64 * 1024;

  auto wsel = [&](int g) { return g == 0 ? Wi : (g == 1 ? Wf : (g == 2 ? Wg : Wo)); };
  const int rb0 = tid >> 2;
  const int rb1 = rb0 + 64;
  const float* bsrc0 =
      wsel((rb0 >> 4) & 3) + (size_t)(nbase + (rb0 >> 6) * 16 + (rb0 & 15)) * 2048 + kofs;
  const float* bsrc1 =
      wsel((rb1 >> 4) & 3) + (size_t)(nbase + (rb1 >> 6) * 16 + (rb1 & 15)) * 2048 + kofs;

  uint4* lA0 = (uint4*)(As + (size_t)tid * 8);
  uint4* lA1 = (uint4*)(As + (size_t)(tid + 256) * 8);
  uint4* lB0 = (uint4*)(Bs + (size_t)tid * 8);
  uint4* lB1 = (uint4*)(Bs + (size_t)(tid + 256) * 8);

  f32x4 acc[4][4] = {};

  for (int kt = 0; kt < 64; ++kt) {
    const int kc = kt * 32;
    const float* abase = (kc < 1024 ? xin : hx) + (kc & 1023);
    const float4 a0lo = *(const float4*)(abase + a_off0);
    const float4 a0hi = *(const float4*)(abase + a_off0 + 4);
    const float4 a1lo = *(const float4*)(abase + a_off1);
    const float4 a1hi = *(const float4*)(abase + a_off1 + 4);
    const float4 b0lo = *(const float4*)(bsrc0 + kc);
    const float4 b0hi = *(const float4*)(bsrc0 + kc + 4);
    const float4 b1lo = *(const float4*)(bsrc1 + kc);
    const float4 b1hi = *(const float4*)(bsrc1 + kc + 4);

    uint4 pa0, pa1, pb0, pb1;
    pa0.x = pack2(a0lo.x, a0lo.y); pa0.y = pack2(a0lo.z, a0lo.w);
    pa0.z = pack2(a0hi.x, a0hi.y); pa0.w = pack2(a0hi.z, a0hi.w);
    pa1.x = pack2(a1lo.x, a1lo.y); pa1.y = pack2(a1lo.z, a1lo.w);
    pa1.z = pack2(a1hi.x, a1hi.y); pa1.w = pack2(a1hi.z, a1hi.w);
    pb0.x = pack2(b0lo.x, b0lo.y); pb0.y = pack2(b0lo.z, b0lo.w);
    pb0.z = pack2(b0hi.x, b0hi.y); pb0.w = pack2(b0hi.z, b0hi.w);
    pb1.x = pack2(b1lo.x, b1lo.y); pb1.y = pack2(b1lo.z, b1lo.w);
    pb1.z = pack2(b1hi.x, b1hi.y); pb1.w = pack2(b1hi.z, b1hi.w);

    __syncthreads();
    *lA0 = pa0; *lA1 = pa1; *lB0 = pb0; *lB1 = pb1;
    __syncthreads();

    bf16x8 a[4], b[4];
#pragma unroll
    for (int i = 0; i < 4; ++i)
      a[i] = *reinterpret_cast<const bf16x8*>(&As[(wr * 64 + i * 16 + lane15) * 32 + quad * 8]);
#pragma unroll
    for (int j = 0; j < 4; ++j)
      b[j] = *reinterpret_cast<const bf16x8*>(&Bs[(wc * 64 + j * 16 + lane15) * 32 + quad * 8]);
#pragma unroll
    for (int i = 0; i < 4; ++i)
#pragma unroll
      for (int j = 0; j < 4; ++j)
        acc[i][j] = __builtin_amdgcn_mfma_f32_16x16x32_bf16(a[i], b[j], acc[i][j], 0, 0, 0);
  }

  const int n = nbase + wc * 16 + lane15;
  const float bias_i = bi[n];
  const float bias_f = bfv[n];
  const float bias_g = bg[n];
  const float bias_o = bo[n];
  float* outh = out;
  float* outc = out + (size_t)4096 * 1024;

#pragma unroll
  for (int i = 0; i < 4; ++i) {
#pragma unroll
    for (int r = 0; r < 4; ++r) {
      const int mb = mbase + wr * 64 + i * 16 + quad * 4 + r;
      const size_t idx = (size_t)mb * 1024 + n;
      const float it = sigmoidf_fast(acc[i][0][r] + bias_i);
      const float ft = sigmoidf_fast(acc[i][1][r] + bias_f);
      const float gt = tanhf_fast(acc[i][2][r] + bias_g);
      const float ot = sigmoidf_fast(acc[i][3][r] + bias_o);
      const float cv = ft * cx[idx] + it * gt;
      const float hv = ot * tanhf_fast(cv);
      outh[idx] = hv;
      outc[idx] = cv;
    }
  }
}

extern "C" void kernel_launch(void* const* d_in, const int* in_sizes, int n_in,
                              void* d_out, int out_size, void* d_ws, size_t ws_size,
                              hipStream_t stream) {
  const float* xin = (const float*)d_in[0];
  const float* hx  = (const float*)d_in[1];
  const float* cx  = (const float*)d_in[2];
  const float* Wi  = (const float*)d_in[3];
  const float* bi  = (const float*)d_in[4];
  const float* Wf  = (const float*)d_in[5];
  const float* bf  = (const float*)d_in[6];
  const float* Wg  = (const float*)d_in[7];
  const float* bg  = (const float*)d_in[8];
  const float* Wo  = (const float*)d_in[9];
  const float* bo  = (const float*)d_in[10];
  float* out = (float*)d_out;

  const size_t need = (size_t)2 * 4096 * 2048 * sizeof(unsigned short);  // 32 MB
  if (ws_size >= need) {
    unsigned short* Xb = (unsigned short*)d_ws;
    unsigned short* Wp = Xb + (size_t)4096 * 2048;
    convert_pack<<<8192, 256, 0, stream>>>(xin, hx, Wi, Wf, Wg, Wo, Xb, Wp);
    dim3 grid(4096 / 128, 1024 / 32);
    lstm_gemm<<<grid, 256, 0, stream>>>(Xb, Wp, cx, bi, bf, bg, bo, out);
  } else {
    dim3 grid(4096 / 128, 1024 / 32);
    lstm_fused_fb<<<grid, 256, 0, stream>>>(xin, hx, cx, Wi, bi, Wf, bf, Wg, bg, Wo, bo, out);
  }
}

// Round 4
// 223.256 us; speedup vs baseline: 1.2989x; 1.0301x over previous
//
#include <hip/hip_runtime.h>
#include <hip/hip_bf16.h>

// LSTM cell, B=4096, IN=1024, H=1024, K = IN+H = 2048. All I/O float32.
// Pass 1 convert_pack: X=concat(input,hx) -> bf16 Xb; W -> bf16 Wp (rows
//   permuted to (gate,hn)-interleaved tile order).
// Pass 2 lstm_gemm: 128x128 MFMA GEMM, global_load_lds staging with
//   XOR-swizzled LDS slots (bank-conflict-free ds_read_b128 fragments),
//   fused LSTM gating epilogue. fp32 accumulate/output.
//
// Swizzle: LDS slot s (16B) holds k-chunk j = (s&3)^((s>>3)&3) of row s>>2.
// Fragment read for (row, quad) -> slot row*4 + (quad ^ ((row>>1)&3));
// since row = C + lane15 with C % 16 == 0, (row>>1)&3 == (lane15>>1)&3.

typedef __attribute__((ext_vector_type(8))) __bf16 bf16x8;
typedef __attribute__((ext_vector_type(4))) float f32x4;

__device__ __forceinline__ unsigned short f2bf(float f) {
  union { float f; unsigned int u; } v; v.f = f;
  unsigned int u = v.u + 0x7FFF + ((v.u >> 16) & 1);  // round-to-nearest-even
  return (unsigned short)(u >> 16);
}
__device__ __forceinline__ unsigned int pack2(float a, float b) {
  return (unsigned int)f2bf(a) | ((unsigned int)f2bf(b) << 16);
}

__device__ __forceinline__ void gld_lds16(const void* g, void* l) {
  __builtin_amdgcn_global_load_lds(
      (const __attribute__((address_space(1))) unsigned int*)g,
      (__attribute__((address_space(3))) unsigned int*)l, 16, 0, 0);
}

__device__ __forceinline__ float sigmoidf_fast(float x) {
  return 1.0f / (1.0f + __expf(-x));
}
__device__ __forceinline__ float tanhf_fast(float x) {
  return 1.0f - 2.0f / (__expf(2.0f * x) + 1.0f);
}

// ---------------- Pass 1: fp32 -> bf16 conversion + W permutation ----------
__global__ __launch_bounds__(256) void convert_pack(
    const float* __restrict__ xin, const float* __restrict__ hx,
    const float* __restrict__ Wi, const float* __restrict__ Wf,
    const float* __restrict__ Wg, const float* __restrict__ Wo,
    unsigned short* __restrict__ Xb, unsigned short* __restrict__ Wp) {
  const int t = blockIdx.x * 256 + threadIdx.x;
  const float* src;
  unsigned short* dst;
  if (t < (1 << 20)) {
    const int e = t * 8;
    const int row = e >> 11, k = e & 2047;
    src = (k < 1024) ? (xin + (size_t)row * 1024 + k)
                     : (hx + (size_t)row * 1024 + (k - 1024));
    dst = Xb + e;
  } else {
    const int e = (t - (1 << 20)) * 8;
    const int g_rb = e >> 11, k = e & 2047;
    const int nb = g_rb >> 7, rb = g_rb & 127;
    const int gate = (rb >> 4) & 3;
    const int hn = (rb >> 6) * 16 + (rb & 15);
    const float* W = gate == 0 ? Wi : (gate == 1 ? Wf : (gate == 2 ? Wg : Wo));
    src = W + (size_t)(nb * 32 + hn) * 2048 + k;
    dst = Wp + e;
  }
  const float4 lo = *(const float4*)src;
  const float4 hi = *(const float4*)(src + 4);
  uint4 p;
  p.x = pack2(lo.x, lo.y);
  p.y = pack2(lo.z, lo.w);
  p.z = pack2(hi.x, hi.y);
  p.w = pack2(hi.z, hi.w);
  *(uint4*)dst = p;
}

// ---------------- Pass 2: MFMA GEMM + fused LSTM gating --------------------
__global__ __launch_bounds__(256) void lstm_gemm(
    const unsigned short* __restrict__ Xb, const unsigned short* __restrict__ Wp,
    const float* __restrict__ cx,
    const float* __restrict__ bi, const float* __restrict__ bfv,
    const float* __restrict__ bg, const float* __restrict__ bo,
    float* __restrict__ out) {
  __shared__ unsigned short As[128 * 32];  // X tile, XOR-swizzled slots
  __shared__ unsigned short Bs[128 * 32];  // W tile, XOR-swizzled slots

  const int tid = threadIdx.x;
  const int lane = tid & 63;
  const int wid = tid >> 6;
  const int wr = wid >> 1, wc = wid & 1;
  const int lane15 = lane & 15, quad = lane >> 4;
  const int qsw = quad ^ ((lane15 >> 1) & 3);  // swizzled quad for frag reads

  const int mbase = blockIdx.x * 128;  // batch tile
  const int nb = blockIdx.y;           // hidden-col tile (32 cols)
  const int nbase = nb * 32;

  // staging: thread owns LDS slots s0=tid, s1=tid+256.
  // slot s holds global chunk (row = s>>2, j = (s&3)^((s>>3)&3)).
  const int s0 = tid, s1 = tid + 256;
  const int r0 = s0 >> 2, j0 = (s0 & 3) ^ ((s0 >> 3) & 3);
  const int r1 = s1 >> 2, j1 = (s1 & 3) ^ ((s1 >> 3) & 3);
  const unsigned short* asrc0 = Xb + (size_t)(mbase + r0) * 2048 + j0 * 8;
  const unsigned short* asrc1 = Xb + (size_t)(mbase + r1) * 2048 + j1 * 8;
  const unsigned short* bsrc0 = Wp + (size_t)(nb * 128 + r0) * 2048 + j0 * 8;
  const unsigned short* bsrc1 = Wp + (size_t)(nb * 128 + r1) * 2048 + j1 * 8;

  unsigned short* lA0 = As + s0 * 8;
  unsigned short* lA1 = As + s1 * 8;
  unsigned short* lB0 = Bs + s0 * 8;
  unsigned short* lB1 = Bs + s1 * 8;

  f32x4 acc[4][4] = {};

  for (int kt = 0; kt < 64; ++kt) {
    const int kc = kt * 32;
    gld_lds16(asrc0 + kc, lA0);
    gld_lds16(asrc1 + kc, lA1);
    gld_lds16(bsrc0 + kc, lB0);
    gld_lds16(bsrc1 + kc, lB1);
    __syncthreads();  // DMA landed + all waves staged

    bf16x8 a[4], b[4];
#pragma unroll
    for (int i = 0; i < 4; ++i)
      a[i] = *reinterpret_cast<const bf16x8*>(&As[(wr * 64 + i * 16 + lane15) * 32 + qsw * 8]);
#pragma unroll
    for (int j = 0; j < 4; ++j)
      b[j] = *reinterpret_cast<const bf16x8*>(&Bs[(wc * 64 + j * 16 + lane15) * 32 + qsw * 8]);
#pragma unroll
    for (int i = 0; i < 4; ++i)
#pragma unroll
      for (int j = 0; j < 4; ++j)
        acc[i][j] = __builtin_amdgcn_mfma_f32_16x16x32_bf16(a[i], b[j], acc[i][j], 0, 0, 0);
    __syncthreads();  // reads done before next iter's DMA overwrites
  }

  // fused LSTM epilogue: acc[i][j], j = gate (0:i 1:f 2:g 3:o);
  // C layout: col=lane&15, row=quad*4+reg
  const int n = nbase + wc * 16 + lane15;
  const float bias_i = bi[n];
  const float bias_f = bfv[n];
  const float bias_g = bg[n];
  const float bias_o = bo[n];

  float* outh = out;
  float* outc = out + (size_t)4096 * 1024;

#pragma unroll
  for (int i = 0; i < 4; ++i) {
#pragma unroll
    for (int r = 0; r < 4; ++r) {
      const int mb = mbase + wr * 64 + i * 16 + quad * 4 + r;
      const size_t idx = (size_t)mb * 1024 + n;
      const float it = sigmoidf_fast(acc[i][0][r] + bias_i);
      const float ft = sigmoidf_fast(acc[i][1][r] + bias_f);
      const float gt = tanhf_fast(acc[i][2][r] + bias_g);
      const float ot = sigmoidf_fast(acc[i][3][r] + bias_o);
      const float cv = ft * cx[idx] + it * gt;
      const float hv = ot * tanhf_fast(cv);
      outh[idx] = hv;
      outc[idx] = cv;
    }
  }
}

// ---------------- Fallback (R2): single fused kernel, no workspace ----------
__global__ __launch_bounds__(256) void lstm_fused_fb(
    const float* __restrict__ xin, const float* __restrict__ hx,
    const float* __restrict__ cx,
    const float* __restrict__ Wi, const float* __restrict__ bi,
    const float* __restrict__ Wf, const float* __restrict__ bfv,
    const float* __restrict__ Wg, const float* __restrict__ bg,
    const float* __restrict__ Wo, const float* __restrict__ bo,
    float* __restrict__ out) {
  __shared__ unsigned short As[128 * 32];
  __shared__ unsigned short Bs[128 * 32];

  const int tid = threadIdx.x;
  const int lane = tid & 63;
  const int wid = tid >> 6;
  const int wr = wid >> 1, wc = wid & 1;
  const int lane15 = lane & 15, quad = lane >> 4;
  const int mbase = blockIdx.x * 128;
  const int nbase = blockIdx.y * 32;

  const int kofs = (tid & 3) * 8;
  const size_t a_off0 = (size_t)(mbase + (tid >> 2)) * 1024 + kofs;
  const size_t a_off1 = a_off0 + (size_t)64 * 1024;

  auto wsel = [&](int g) { return g == 0 ? Wi : (g == 1 ? Wf : (g == 2 ? Wg : Wo)); };
  const int rb0 = tid >> 2;
  const int rb1 = rb0 + 64;
  const float* bsrc0 =
      wsel((rb0 >> 4) & 3) + (size_t)(nbase + (rb0 >> 6) * 16 + (rb0 & 15)) * 2048 + kofs;
  const float* bsrc1 =
      wsel((rb1 >> 4) & 3) + (size_t)(nbase + (rb1 >> 6) * 16 + (rb1 & 15)) * 2048 + kofs;

  uint4* lA0 = (uint4*)(As + (size_t)tid * 8);
  uint4* lA1 = (uint4*)(As + (size_t)(tid + 256) * 8);
  uint4* lB0 = (uint4*)(Bs + (size_t)tid * 8);
  uint4* lB1 = (uint4*)(Bs + (size_t)(tid + 256) * 8);

  f32x4 acc[4][4] = {};

  for (int kt = 0; kt < 64; ++kt) {
    const int kc = kt * 32;
    const float* abase = (kc < 1024 ? xin : hx) + (kc & 1023);
    const float4 a0lo = *(const float4*)(abase + a_off0);
    const float4 a0hi = *(const float4*)(abase + a_off0 + 4);
    const float4 a1lo = *(const float4*)(abase + a_off1);
    const float4 a1hi = *(const float4*)(abase + a_off1 + 4);
    const float4 b0lo = *(const float4*)(bsrc0 + kc);
    const float4 b0hi = *(const float4*)(bsrc0 + kc + 4);
    const float4 b1lo = *(const float4*)(bsrc1 + kc);
    const float4 b1hi = *(const float4*)(bsrc1 + kc + 4);

    uint4 pa0, pa1, pb0, pb1;
    pa0.x = pack2(a0lo.x, a0lo.y); pa0.y = pack2(a0lo.z, a0lo.w);
    pa0.z = pack2(a0hi.x, a0hi.y); pa0.w = pack2(a0hi.z, a0hi.w);
    pa1.x = pack2(a1lo.x, a1lo.y); pa1.y = pack2(a1lo.z, a1lo.w);
    pa1.z = pack2(a1hi.x, a1hi.y); pa1.w = pack2(a1hi.z, a1hi.w);
    pb0.x = pack2(b0lo.x, b0lo.y); pb0.y = pack2(b0lo.z, b0lo.w);
    pb0.z = pack2(b0hi.x, b0hi.y); pb0.w = pack2(b0hi.z, b0hi.w);
    pb1.x = pack2(b1lo.x, b1lo.y); pb1.y = pack2(b1lo.z, b1lo.w);
    pb1.z = pack2(b1hi.x, b1hi.y); pb1.w = pack2(b1hi.z, b1hi.w);

    __syncthreads();
    *lA0 = pa0; *lA1 = pa1; *lB0 = pb0; *lB1 = pb1;
    __syncthreads();

    bf16x8 a[4], b[4];
#pragma unroll
    for (int i = 0; i < 4; ++i)
      a[i] = *reinterpret_cast<const bf16x8*>(&As[(wr * 64 + i * 16 + lane15) * 32 + quad * 8]);
#pragma unroll
    for (int j = 0; j < 4; ++j)
      b[j] = *reinterpret_cast<const bf16x8*>(&Bs[(wc * 64 + j * 16 + lane15) * 32 + quad * 8]);
#pragma unroll
    for (int i = 0; i < 4; ++i)
#pragma unroll
      for (int j = 0; j < 4; ++j)
        acc[i][j] = __builtin_amdgcn_mfma_f32_16x16x32_bf16(a[i], b[j], acc[i][j], 0, 0, 0);
  }

  const int n = nbase + wc * 16 + lane15;
  const float bias_i = bi[n];
  const float bias_f = bfv[n];
  const float bias_g = bg[n];
  const float bias_o = bo[n];
  float* outh = out;
  float* outc = out + (size_t)4096 * 1024;

#pragma unroll
  for (int i = 0; i < 4; ++i) {
#pragma unroll
    for (int r = 0; r < 4; ++r) {
      const int mb = mbase + wr * 64 + i * 16 + quad * 4 + r;
      const size_t idx = (size_t)mb * 1024 + n;
      const float it = sigmoidf_fast(acc[i][0][r] + bias_i);
      const float ft = sigmoidf_fast(acc[i][1][r] + bias_f);
      const float gt = tanhf_fast(acc[i][2][r] + bias_g);
      const float ot = sigmoidf_fast(acc[i][3][r] + bias_o);
      const float cv = ft * cx[idx] + it * gt;
      const float hv = ot * tanhf_fast(cv);
      outh[idx] = hv;
      outc[idx] = cv;
    }
  }
}

extern "C" void kernel_launch(void* const* d_in, const int* in_sizes, int n_in,
                              void* d_out, int out_size, void* d_ws, size_t ws_size,
                              hipStream_t stream) {
  const float* xin = (const float*)d_in[0];
  const float* hx  = (const float*)d_in[1];
  const float* cx  = (const float*)d_in[2];
  const float* Wi  = (const float*)d_in[3];
  const float* bi  = (const float*)d_in[4];
  const float* Wf  = (const float*)d_in[5];
  const float* bf  = (const float*)d_in[6];
  const float* Wg  = (const float*)d_in[7];
  const float* bg  = (const float*)d_in[8];
  const float* Wo  = (const float*)d_in[9];
  const float* bo  = (const float*)d_in[10];
  float* out = (float*)d_out;

  const size_t need = (size_t)2 * 4096 * 2048 * sizeof(unsigned short);  // 32 MB
  if (ws_size >= need) {
    unsigned short* Xb = (unsigned short*)d_ws;
    unsigned short* Wp = Xb + (size_t)4096 * 2048;
    convert_pack<<<8192, 256, 0, stream>>>(xin, hx, Wi, Wf, Wg, Wo, Xb, Wp);
    dim3 grid(4096 / 128, 1024 / 32);
    lstm_gemm<<<grid, 256, 0, stream>>>(Xb, Wp, cx, bi, bf, bg, bo, out);
  } else {
    dim3 grid(4096 / 128, 1024 / 32);
    lstm_fused_fb<<<grid, 256, 0, stream>>>(xin, hx, cx, Wi, bi, Wf, bf, Wg, bg, Wo, bo, out);
  }
}